// Round 10
// baseline (162.042 us; speedup 1.0000x reference)
//
#include <hip/hip_runtime.h>
#include <hip/hip_bf16.h>

#define N_TOTAL 8192
#define BROWS   4096
#define DDIM    256
#define NCLS    10
#define NPAN    64              // 128-row panels
#define NTILE   4160            // sum over panels of (128-2*bi) 128x64 tiles (= 8*520)

typedef __attribute__((ext_vector_type(8))) short bf16x8;
typedef __attribute__((ext_vector_type(4))) float f32x4;
typedef __attribute__((ext_vector_type(2))) float f32x2;

// ---- workspace layout (bytes) ----
static constexpr size_t OFF_X    = 0;              // 8192*256*2 = 4 MiB bf16 data
static constexpr size_t OFF_SQ   = 0x400000;       // 8192 f32 row sq-norms
static constexpr size_t OFF_XU   = 0x408000;       // 8192*32 bf16 padded weights
static constexpr size_t OFF_CP   = 0x488000;       // 64*256 f32 col partials
static constexpr size_t OFF_CLS  = 0x498000;       // 32*20 f32 class partials
static constexpr size_t OFF_PRES = 0x499000;       // 32 u32 presence partials
static constexpr size_t OFF_SC   = 0x49A000;       // 32 f32 scalars
static constexpr size_t OFF_CTR  = 0x49A800;       // u32 completion counter
static constexpr size_t OFF_PART = 0x49B000;       // 4160 f64 block partials

// scal: [0] = -1/(16*bw) (natural log), [5] = count_safe

__device__ __forceinline__ void gload_lds16(const void* g, void* l) {
    __builtin_amdgcn_global_load_lds((const __attribute__((address_space(1))) void*)g,
                                     (__attribute__((address_space(3))) void*)l, 16, 0, 0);
}
__device__ __forceinline__ float rne_bf16_val(float x) {
    unsigned b = __float_as_uint(x);
    unsigned r = (b + 0x7FFFu + ((b >> 16) & 1u)) >> 16;
    return __uint_as_float(r << 16);
}

// ---------------------------------------------------------------------------
// 1) fused pre-pass (also zeroes the completion counter)
// ---------------------------------------------------------------------------
__global__ void k_pre(const float* __restrict__ src, const float* __restrict__ tgt,
                      const float* __restrict__ label, const float* __restrict__ logits,
                      unsigned short* __restrict__ X, float* __restrict__ sq,
                      float* __restrict__ colpart, float* __restrict__ clspart,
                      unsigned* __restrict__ prespart, unsigned* __restrict__ ctr) {
    __shared__ float shbuf[8][256];
    __shared__ float cbuf[256][NCLS];
    __shared__ unsigned pm[128];
    int t = threadIdx.x;
    int bid = blockIdx.x;
    if (bid == 0 && t == 0) *ctr = 0u;

    if (bid < 2048) {                 // ---- prep path
        int wid  = t >> 6;
        int lane = t & 63;
        int row  = bid * 4 + wid;
        const float* p = (row < BROWS) ? (src + (size_t)row * DDIM)
                                       : (tgt + (size_t)(row - BROWS) * DDIM);
        f32x4 v = *reinterpret_cast<const f32x4*>(p + lane * 4);
        unsigned short h[4];
        float ssum = 0.f;
#pragma unroll
        for (int e = 0; e < 4; ++e) {
            unsigned bits = __float_as_uint(v[e]);
            unsigned r = (bits + 0x7FFFu + ((bits >> 16) & 1u)) >> 16;
            h[e] = (unsigned short)r;
            float f = __uint_as_float(r << 16);
            ssum += f * f;
        }
        ushort4 us; us.x = h[0]; us.y = h[1]; us.z = h[2]; us.w = h[3];
        *reinterpret_cast<ushort4*>(X + (size_t)row * DDIM + lane * 4) = us;
#pragma unroll
        for (int off = 32; off > 0; off >>= 1) ssum += __shfl_xor(ssum, off);
        if (lane == 0) sq[row] = ssum;
    } else if (bid < 2112) {          // ---- colsum path (from f32 source, RNE inline)
        int b  = bid - 2048;
        int cg = t & 31;
        int rs = t >> 5;
        const float* base = (b < 32)
            ? (src + ((size_t)(b * 128 + rs)) * DDIM + cg * 8)
            : (tgt + ((size_t)((b - 32) * 128 + rs)) * DDIM + cg * 8);
        float a[8];
#pragma unroll
        for (int e = 0; e < 8; ++e) a[e] = 0.f;
        for (int i = 0; i < 16; ++i) {
            const float* rp = base + (size_t)i * 8 * DDIM;
            f32x4 v0 = *reinterpret_cast<const f32x4*>(rp);
            f32x4 v1 = *reinterpret_cast<const f32x4*>(rp + 4);
#pragma unroll
            for (int e = 0; e < 4; ++e) a[e]     += rne_bf16_val(v0[e]);
#pragma unroll
            for (int e = 0; e < 4; ++e) a[4 + e] += rne_bf16_val(v1[e]);
        }
#pragma unroll
        for (int e = 0; e < 8; ++e) shbuf[rs][cg * 8 + e] = a[e];
        __syncthreads();
        float s = 0.f;
#pragma unroll
        for (int k = 0; k < 8; ++k) s += shbuf[k][t];
        colpart[b * DDIM + t] = s;
    } else {                          // ---- class-sum path
        int b = bid - 2112;
        int r = b * 128 + (t & 127);
        if (t < 128) {
            const float* lr = label + (size_t)r * NCLS;
#pragma unroll
            for (int c = 0; c < NCLS; ++c) cbuf[t][c] = lr[c];
        } else {
            const float* gr = logits + (size_t)r * NCLS;
            float bv = -1e30f; int bc = 0;
#pragma unroll
            for (int c = 0; c < NCLS; ++c) {
                float v = gr[c];
                cbuf[t][c] = v;
                if (v > bv) { bv = v; bc = c; }
            }
            pm[t - 128] = 1u << bc;
        }
        __syncthreads();
        if (t < NCLS) {
            float a = 0.f;
            for (int i = 0; i < 128; ++i) a += cbuf[i][t];
            clspart[b * 20 + t] = a;
        } else if (t < 2 * NCLS) {
            float a = 0.f;
            for (int i = 128; i < 256; ++i) a += cbuf[i][t - NCLS];
            clspart[b * 20 + t] = a;
        }
        if (t == 0) {
            unsigned p = 0;
            for (int i = 0; i < 128; ++i) p |= pm[i];
            prespart[b] = p;
        }
    }
}

// ---------------------------------------------------------------------------
// 2) scales + XU build fused (33 blocks)
// ---------------------------------------------------------------------------
__global__ void k_scales(const float* __restrict__ clspart, const unsigned* __restrict__ prespart,
                         const float* __restrict__ colpart, const float* __restrict__ sq,
                         const float* __restrict__ label, const float* __restrict__ logits,
                         float* __restrict__ scal, unsigned short* __restrict__ XU) {
    __shared__ float  cfin[2 * NCLS];
    __shared__ float  ascale[NCLS], bscale[NCLS];
    __shared__ unsigned presAll;
    __shared__ double dred[256];
    int t = threadIdx.x, b = blockIdx.x;

    if (t < 2 * NCLS) {
        float a = 0.f;
        for (int k = 0; k < 32; ++k) a += clspart[k * 20 + t];
        cfin[t] = a;
    }
    if (t == 0) {
        unsigned p = 0;
        for (int k = 0; k < 32; ++k) p |= prespart[k];
        presAll = p;
    }
    __syncthreads();
    if (t == 0) {
        int count = 0;
        for (int c = 0; c < NCLS; ++c) {
            float sv = cfin[c], tv = cfin[NCLS + c];
            bool m = (sv > 0.f) && ((presAll >> c) & 1u);
            count += m ? 1 : 0;
            float sdiv = (sv == 0.f) ? 100.f : sv;
            float tdiv = (tv == 0.f) ? 100.f : tv;
            ascale[c] = m ? (1.f / sdiv) : 0.f;
            bscale[c] = m ? (1.f / tdiv) : 0.f;
        }
        if (b == 32) scal[5] = (float)(count > 0 ? count : 1);
    }
    __syncthreads();

    if (b < 32) {                     // ---- XU rows
        int r = b * 256 + t;
        float v[NCLS];
        if (r < BROWS) {
            const float* lr = label + (size_t)r * NCLS;
#pragma unroll
            for (int c = 0; c < NCLS; ++c) v[c] = lr[c] * ascale[c];
        } else {
            const float* gr = logits + (size_t)(r - BROWS) * NCLS;
#pragma unroll
            for (int c = 0; c < NCLS; ++c) v[c] = -gr[c] * bscale[c];
        }
        unsigned packed[16];
#pragma unroll
        for (int w = 0; w < 16; ++w) {
            unsigned lo = 0, hi = 0;
            if (2 * w < NCLS) {
                unsigned bits = __float_as_uint(v[2 * w]);
                lo = (bits + 0x7FFFu + ((bits >> 16) & 1u)) >> 16;
            }
            if (2 * w + 1 < NCLS) {
                unsigned bits = __float_as_uint(v[2 * w + 1]);
                hi = (bits + 0x7FFFu + ((bits >> 16) & 1u)) >> 16;
            }
            packed[w] = lo | (hi << 16);
        }
        uint4* out = reinterpret_cast<uint4*>(XU + (size_t)r * 32);
#pragma unroll
        for (int q = 0; q < 4; ++q)
            out[q] = make_uint4(packed[4*q], packed[4*q+1], packed[4*q+2], packed[4*q+3]);
    } else {                          // ---- bandwidth (block 32)
        double cd = 0.0;
        for (int k = 0; k < 64; ++k) cd += (double)colpart[k * DDIM + t];
        dred[t] = cd * cd;
        __syncthreads();
        for (int s = 128; s > 0; s >>= 1) { if (t < s) dred[t] += dred[t + s]; __syncthreads(); }
        double S_cs = dred[0];
        __syncthreads();
        double ss = 0.0;
        for (int k = 0; k < 32; ++k) ss += (double)sq[t + 256 * k];
        dred[t] = ss;
        __syncthreads();
        for (int s = 128; s > 0; s >>= 1) { if (t < s) dred[t] += dred[t + s]; __syncthreads(); }
        if (t == 0) {
            double nf = (double)N_TOTAL;
            double sum_l2 = 2.0 * nf * dred[0] - 2.0 * S_cs;
            if (sum_l2 < 0.0) sum_l2 = 0.0;
            double bw = sum_l2 / (nf * nf - nf) / 4.0;
            scal[0] = (float)(-1.0 / (16.0 * bw));
        }
    }
}

// ---------------------------------------------------------------------------
// 3) main: 128x64 tiles, 128 threads / 2 waves, R4's exact BK=32 double-buffer
//    __syncthreads schedule, linear staging, ~25.6 KB LDS -> 6 blocks/CU.
//    Diagonal-straddling tiles get a per-pair 0/1/2 factor; others x2.
// ---------------------------------------------------------------------------
__global__ __launch_bounds__(128, 3) void k_main(const unsigned short* __restrict__ X,
                                                 const unsigned short* __restrict__ XU,
                                                 const float* __restrict__ sq,
                                                 const float* __restrict__ scal,
                                                 double* __restrict__ partials,
                                                 unsigned* __restrict__ ctr,
                                                 float* __restrict__ out) {
    // XCD-contiguous bid swizzle (4160 = 8*520, bijective)
    int bid = (blockIdx.x & 7) * (NTILE / 8) + (blockIdx.x >> 3);
    // decode (panel bi, j-tile) : panel bi has 128-2*bi tiles, j64 = 2*bi + rem
    int bi = 0, rem = bid;
    while (rem >= 128 - 2 * bi) { rem -= 128 - 2 * bi; ++bi; }
    int j64 = 2 * bi + rem;
    bool partial = (rem < 2);          // tile overlaps the diagonal 128x128 block

    int tid = threadIdx.x, lane = tid & 63, wid = tid >> 6;
    int lrow = lane & 15, kgrp = lane >> 4;

    __shared__ unsigned short Abuf[2 * 128 * 32];   // [buf][128 rows][32 k-shorts]
    __shared__ unsigned short Bbuf[2 * 64 * 32];    // [buf][64 rows][32 k-shorts]
    __shared__ double dred2[128];
    __shared__ float red[2];
    __shared__ unsigned lastflag;
    char* AB = (char*)Abuf;
    char* BB = (char*)Bbuf;

    f32x4 acc[4][4];
#pragma unroll
    for (int a = 0; a < 4; ++a)
#pragma unroll
        for (int b = 0; b < 4; ++b) acc[a][b] = (f32x4){0.f, 0.f, 0.f, 0.f};

    // staging: LINEAR source & dest. A: 512 chunks (4/thread), B: 256 (2/thread)
    int srow = tid >> 2, scol = (tid & 3) * 8;
    const unsigned short* gA0 = X + ((size_t)bi * 128 +  0 + srow) * DDIM + scol;
    const unsigned short* gA1 = X + ((size_t)bi * 128 + 32 + srow) * DDIM + scol;
    const unsigned short* gA2 = X + ((size_t)bi * 128 + 64 + srow) * DDIM + scol;
    const unsigned short* gA3 = X + ((size_t)bi * 128 + 96 + srow) * DDIM + scol;
    const unsigned short* gB0 = X + ((size_t)j64 * 64 +  0 + srow) * DDIM + scol;
    const unsigned short* gB1 = X + ((size_t)j64 * 64 + 32 + srow) * DDIM + scol;
    int lds0 = tid * 16;
    int aoff = (wid * 64 + lrow) * 64 + kgrp * 16;   // + f*1024
    int boff = lrow * 64 + kgrp * 16;                // + g*1024

#define STAGE(BS, KS) do { \
    gload_lds16(gA0 + (KS) * 32, AB + (BS) * 8192 + lds0); \
    gload_lds16(gA1 + (KS) * 32, AB + (BS) * 8192 + lds0 + 2048); \
    gload_lds16(gA2 + (KS) * 32, AB + (BS) * 8192 + lds0 + 4096); \
    gload_lds16(gA3 + (KS) * 32, AB + (BS) * 8192 + lds0 + 6144); \
    gload_lds16(gB0 + (KS) * 32, BB + (BS) * 4096 + lds0); \
    gload_lds16(gB1 + (KS) * 32, BB + (BS) * 4096 + lds0 + 2048); \
} while (0)

#define COMPUTE(BS) do { \
    bf16x8 af[4], bf_[4]; \
    _Pragma("unroll") \
    for (int f = 0; f < 4; ++f) { \
        af[f]  = *reinterpret_cast<const bf16x8*>(AB + (BS) * 8192 + aoff + f * 1024); \
        bf_[f] = *reinterpret_cast<const bf16x8*>(BB + (BS) * 4096 + boff + f * 1024); \
    } \
    _Pragma("unroll") \
    for (int a = 0; a < 4; ++a) \
        _Pragma("unroll") \
        for (int b = 0; b < 4; ++b) \
            acc[a][b] = __builtin_amdgcn_mfma_f32_16x16x32_bf16(af[a], bf_[b], acc[a][b], 0, 0, 0); \
} while (0)

    STAGE(0, 0);
    __syncthreads();
#pragma unroll
    for (int t = 0; t < 7; ++t) {
        STAGE((t + 1) & 1, t + 1);     // issue next-slice loads first
        COMPUTE(t & 1);                // compute current slice
        __syncthreads();               // drain + protect
    }

    // light epilogue prefetch overlapping final MFMAs
    int i0 = bi * 128 + wid * 64;
    int j0 = j64 * 64;
    f32x4 sqin[4];
#pragma unroll
    for (int f = 0; f < 4; ++f)
        sqin[f] = *reinterpret_cast<const f32x4*>(sq + i0 + f * 16 + kgrp * 4);
    float sqjn[4];
#pragma unroll
    for (int g = 0; g < 4; ++g) sqjn[g] = sq[j0 + g * 16 + lrow];
    float nbv = scal[0];

    COMPUTE(1);                        // last K-slice (ks=7)

    const unsigned short* AU = XU + (size_t)(i0 + lrow) * 32 + kgrp * 8;
    const unsigned short* BU = XU + (size_t)(j0 + lrow) * 32 + kgrp * 8;
    bf16x8 au[4];
#pragma unroll
    for (int f = 0; f < 4; ++f)
        au[f] = *reinterpret_cast<const bf16x8*>(AU + (size_t)f * 16 * 32);

#pragma unroll
    for (int f = 0; f < 4; ++f) sqin[f] *= nbv;
#pragma unroll
    for (int g = 0; g < 4; ++g) sqjn[g] *= nbv;
    float m2nb = -2.f * nbv;

    f32x2 lp2 = (f32x2){0.f, 0.f};
#pragma unroll
    for (int g = 0; g < 4; ++g) {
        bf16x8 bu = *reinterpret_cast<const bf16x8*>(BU + (size_t)g * 16 * 32);
        int jj = j0 + g * 16 + lrow;
        f32x4 wf[4];
#pragma unroll
        for (int f = 0; f < 4; ++f) {
            wf[f] = __builtin_amdgcn_mfma_f32_16x16x32_bf16(au[f], bu, (f32x4){0.f,0.f,0.f,0.f}, 0, 0, 0);
            if (partial) {
                int iib = i0 + f * 16 + kgrp * 4;
                f32x4 fac;
#pragma unroll
                for (int r = 0; r < 4; ++r) {
                    int d = jj - (iib + r);
                    fac[r] = (d < 0) ? 0.f : ((d == 0) ? 1.f : 2.f);
                }
                wf[f] *= fac;
            }
        }
#pragma unroll
        for (int f = 0; f < 4; ++f) {
#pragma unroll
            for (int h = 0; h < 2; ++h) {
                f32x2 ssn = (f32x2){ sqin[f][2*h] + sqjn[g], sqin[f][2*h+1] + sqjn[g] };
                f32x2 tt  = (f32x2){ fmaf(acc[f][g][2*h],   m2nb, ssn.x),
                                     fmaf(acc[f][g][2*h+1], m2nb, ssn.y) };
                tt.x = fminf(tt.x, 0.f);
                tt.y = fminf(tt.y, 0.f);
                f32x2 e;
                e.x = __expf(tt.x);
                e.y = __expf(tt.y);
                f32x2 e2 = e * e, e4 = e2 * e2, e8 = e4 * e4, e16 = e8 * e8;
                f32x2 ks = ((e + e2) + (e4 + e8)) + e16;
                lp2.x = fmaf(wf[f][2*h],   ks.x, lp2.x);
                lp2.y = fmaf(wf[f][2*h+1], ks.y, lp2.y);
            }
        }
    }
    float lp = lp2.x + lp2.y;

#pragma unroll
    for (int off = 32; off > 0; off >>= 1) lp += __shfl_xor(lp, off);
    if (lane == 0) red[wid] = lp;
    __syncthreads();
    if (tid == 0) {
        partials[bid] = (double)(red[0] + red[1]) * (partial ? 1.0 : 2.0);
        __threadfence();
        unsigned old = atomicAdd(ctr, 1u);
        lastflag = (old == NTILE - 1) ? 1u : 0u;
    }
    __syncthreads();

    if (lastflag) {                    // last block: fixed-order final reduction
        __threadfence();
        const volatile double* vp = partials;
        double s = 0.0;
        for (int k = 0; k < 33; ++k) {
            int idx = tid + 128 * k;
            if (idx < NTILE) s += vp[idx];
        }
        dred2[tid] = s;
        __syncthreads();
        for (int st = 64; st > 0; st >>= 1) {
            if (tid < st) dred2[tid] += dred2[tid + st];
            __syncthreads();
        }
        if (tid == 0) out[0] = (float)(dred2[0] / (double)scal[5]);
    }
#undef STAGE
#undef COMPUTE
}

extern "C" void kernel_launch(void* const* d_in, const int* in_sizes, int n_in,
                              void* d_out, int out_size, void* d_ws, size_t ws_size,
                              hipStream_t stream) {
    const float* src    = (const float*)d_in[0];
    const float* tgt    = (const float*)d_in[1];
    const float* label  = (const float*)d_in[2];
    const float* logits = (const float*)d_in[3];

    char* ws = (char*)d_ws;
    unsigned short* X   = (unsigned short*)(ws + OFF_X);
    float* sq           = (float*)(ws + OFF_SQ);
    unsigned short* XU  = (unsigned short*)(ws + OFF_XU);
    float* colpart      = (float*)(ws + OFF_CP);
    float* clspart      = (float*)(ws + OFF_CLS);
    unsigned* prespart  = (unsigned*)(ws + OFF_PRES);
    float* scal         = (float*)(ws + OFF_SC);
    unsigned* ctr       = (unsigned*)(ws + OFF_CTR);
    double* partials    = (double*)(ws + OFF_PART);

    k_pre    <<<2144,  256, 0, stream>>>(src, tgt, label, logits, X, sq, colpart, clspart, prespart, ctr);
    k_scales <<<33,    256, 0, stream>>>(clspart, prespart, colpart, sq, label, logits, scal, XU);
    k_main   <<<NTILE, 128, 0, stream>>>(X, XU, sq, scal, partials, ctr, (float*)d_out);
}

// Round 11
// 100.425 us; speedup vs baseline: 1.6136x; 1.6136x over previous
//
#include <hip/hip_runtime.h>
#include <hip/hip_bf16.h>

#define N_TOTAL 8192
#define BROWS   4096
#define DDIM    256
#define NCLS    10
#define NB      64              // 128-row tiles per side
#define NTRI    (NB*(NB+1)/2)   // 2080 upper-tri blocks (= 8*260)
#define K_STEPS 8               // BK=32

typedef __attribute__((ext_vector_type(8))) short bf16x8;
typedef __attribute__((ext_vector_type(4))) float f32x4;
typedef __attribute__((ext_vector_type(2))) float f32x2;

// ---- workspace layout (bytes) ----
static constexpr size_t OFF_X    = 0;              // 8192*256*2 = 4 MiB bf16 data
static constexpr size_t OFF_SQ   = 0x400000;       // 8192 f32 row sq-norms
static constexpr size_t OFF_XU   = 0x408000;       // 8192*32 bf16 padded weights
static constexpr size_t OFF_CP   = 0x488000;       // 64*256 f32 col partials
static constexpr size_t OFF_CLS  = 0x498000;       // 32*20 f32 class partials
static constexpr size_t OFF_PRES = 0x499000;       // 32 u32 presence partials
static constexpr size_t OFF_SC   = 0x49A000;       // 32 f32 scalars
static constexpr size_t OFF_CTR  = 0x49A800;       // u32 completion counter
static constexpr size_t OFF_PART = 0x49B000;       // 2080 f64 block partials

// scal: [0] = -1/(16*bw) (natural log), [5] = count_safe

__device__ __forceinline__ void gload_lds16(const void* g, void* l) {
    __builtin_amdgcn_global_load_lds((const __attribute__((address_space(1))) void*)g,
                                     (__attribute__((address_space(3))) void*)l, 16, 0, 0);
}
__device__ __forceinline__ float rne_bf16_val(float x) {
    unsigned b = __float_as_uint(x);
    unsigned r = (b + 0x7FFFu + ((b >> 16) & 1u)) >> 16;
    return __uint_as_float(r << 16);
}

// ---------------------------------------------------------------------------
// 1) fused pre-pass (also zeroes the completion counter)
// ---------------------------------------------------------------------------
__global__ void k_pre(const float* __restrict__ src, const float* __restrict__ tgt,
                      const float* __restrict__ label, const float* __restrict__ logits,
                      unsigned short* __restrict__ X, float* __restrict__ sq,
                      float* __restrict__ colpart, float* __restrict__ clspart,
                      unsigned* __restrict__ prespart, unsigned* __restrict__ ctr) {
    __shared__ float shbuf[8][256];
    __shared__ float cbuf[256][NCLS];
    __shared__ unsigned pm[128];
    int t = threadIdx.x;
    int bid = blockIdx.x;
    if (bid == 0 && t == 0) *ctr = 0u;

    if (bid < 2048) {                 // ---- prep path
        int wid  = t >> 6;
        int lane = t & 63;
        int row  = bid * 4 + wid;
        const float* p = (row < BROWS) ? (src + (size_t)row * DDIM)
                                       : (tgt + (size_t)(row - BROWS) * DDIM);
        f32x4 v = *reinterpret_cast<const f32x4*>(p + lane * 4);
        unsigned short h[4];
        float ssum = 0.f;
#pragma unroll
        for (int e = 0; e < 4; ++e) {
            unsigned bits = __float_as_uint(v[e]);
            unsigned r = (bits + 0x7FFFu + ((bits >> 16) & 1u)) >> 16;
            h[e] = (unsigned short)r;
            float f = __uint_as_float(r << 16);
            ssum += f * f;
        }
        ushort4 us; us.x = h[0]; us.y = h[1]; us.z = h[2]; us.w = h[3];
        *reinterpret_cast<ushort4*>(X + (size_t)row * DDIM + lane * 4) = us;
#pragma unroll
        for (int off = 32; off > 0; off >>= 1) ssum += __shfl_xor(ssum, off);
        if (lane == 0) sq[row] = ssum;
    } else if (bid < 2112) {          // ---- colsum path (from f32 source, RNE inline)
        int b  = bid - 2048;
        int cg = t & 31;
        int rs = t >> 5;
        const float* base = (b < 32)
            ? (src + ((size_t)(b * 128 + rs)) * DDIM + cg * 8)
            : (tgt + ((size_t)((b - 32) * 128 + rs)) * DDIM + cg * 8);
        float a[8];
#pragma unroll
        for (int e = 0; e < 8; ++e) a[e] = 0.f;
        for (int i = 0; i < 16; ++i) {
            const float* rp = base + (size_t)i * 8 * DDIM;
            f32x4 v0 = *reinterpret_cast<const f32x4*>(rp);
            f32x4 v1 = *reinterpret_cast<const f32x4*>(rp + 4);
#pragma unroll
            for (int e = 0; e < 4; ++e) a[e]     += rne_bf16_val(v0[e]);
#pragma unroll
            for (int e = 0; e < 4; ++e) a[4 + e] += rne_bf16_val(v1[e]);
        }
#pragma unroll
        for (int e = 0; e < 8; ++e) shbuf[rs][cg * 8 + e] = a[e];
        __syncthreads();
        float s = 0.f;
#pragma unroll
        for (int k = 0; k < 8; ++k) s += shbuf[k][t];
        colpart[b * DDIM + t] = s;
    } else {                          // ---- class-sum path
        int b = bid - 2112;
        int r = b * 128 + (t & 127);
        if (t < 128) {
            const float* lr = label + (size_t)r * NCLS;
#pragma unroll
            for (int c = 0; c < NCLS; ++c) cbuf[t][c] = lr[c];
        } else {
            const float* gr = logits + (size_t)r * NCLS;
            float bv = -1e30f; int bc = 0;
#pragma unroll
            for (int c = 0; c < NCLS; ++c) {
                float v = gr[c];
                cbuf[t][c] = v;
                if (v > bv) { bv = v; bc = c; }
            }
            pm[t - 128] = 1u << bc;
        }
        __syncthreads();
        if (t < NCLS) {
            float a = 0.f;
            for (int i = 0; i < 128; ++i) a += cbuf[i][t];
            clspart[b * 20 + t] = a;
        } else if (t < 2 * NCLS) {
            float a = 0.f;
            for (int i = 128; i < 256; ++i) a += cbuf[i][t - NCLS];
            clspart[b * 20 + t] = a;
        }
        if (t == 0) {
            unsigned p = 0;
            for (int i = 0; i < 128; ++i) p |= pm[i];
            prespart[b] = p;
        }
    }
}

// ---------------------------------------------------------------------------
// 2) scales + XU build fused (33 blocks)
// ---------------------------------------------------------------------------
__global__ void k_scales(const float* __restrict__ clspart, const unsigned* __restrict__ prespart,
                         const float* __restrict__ colpart, const float* __restrict__ sq,
                         const float* __restrict__ label, const float* __restrict__ logits,
                         float* __restrict__ scal, unsigned short* __restrict__ XU) {
    __shared__ float  cfin[2 * NCLS];
    __shared__ float  ascale[NCLS], bscale[NCLS];
    __shared__ unsigned presAll;
    __shared__ double dred[256];
    int t = threadIdx.x, b = blockIdx.x;

    if (t < 2 * NCLS) {
        float a = 0.f;
        for (int k = 0; k < 32; ++k) a += clspart[k * 20 + t];
        cfin[t] = a;
    }
    if (t == 0) {
        unsigned p = 0;
        for (int k = 0; k < 32; ++k) p |= prespart[k];
        presAll = p;
    }
    __syncthreads();
    if (t == 0) {
        int count = 0;
        for (int c = 0; c < NCLS; ++c) {
            float sv = cfin[c], tv = cfin[NCLS + c];
            bool m = (sv > 0.f) && ((presAll >> c) & 1u);
            count += m ? 1 : 0;
            float sdiv = (sv == 0.f) ? 100.f : sv;
            float tdiv = (tv == 0.f) ? 100.f : tv;
            ascale[c] = m ? (1.f / sdiv) : 0.f;
            bscale[c] = m ? (1.f / tdiv) : 0.f;
        }
        if (b == 32) scal[5] = (float)(count > 0 ? count : 1);
    }
    __syncthreads();

    if (b < 32) {                     // ---- XU rows
        int r = b * 256 + t;
        float v[NCLS];
        if (r < BROWS) {
            const float* lr = label + (size_t)r * NCLS;
#pragma unroll
            for (int c = 0; c < NCLS; ++c) v[c] = lr[c] * ascale[c];
        } else {
            const float* gr = logits + (size_t)(r - BROWS) * NCLS;
#pragma unroll
            for (int c = 0; c < NCLS; ++c) v[c] = -gr[c] * bscale[c];
        }
        unsigned packed[16];
#pragma unroll
        for (int w = 0; w < 16; ++w) {
            unsigned lo = 0, hi = 0;
            if (2 * w < NCLS) {
                unsigned bits = __float_as_uint(v[2 * w]);
                lo = (bits + 0x7FFFu + ((bits >> 16) & 1u)) >> 16;
            }
            if (2 * w + 1 < NCLS) {
                unsigned bits = __float_as_uint(v[2 * w + 1]);
                hi = (bits + 0x7FFFu + ((bits >> 16) & 1u)) >> 16;
            }
            packed[w] = lo | (hi << 16);
        }
        uint4* out = reinterpret_cast<uint4*>(XU + (size_t)r * 32);
#pragma unroll
        for (int q = 0; q < 4; ++q)
            out[q] = make_uint4(packed[4*q], packed[4*q+1], packed[4*q+2], packed[4*q+3]);
    } else {                          // ---- bandwidth (block 32)
        double cd = 0.0;
        for (int k = 0; k < 64; ++k) cd += (double)colpart[k * DDIM + t];
        dred[t] = cd * cd;
        __syncthreads();
        for (int s = 128; s > 0; s >>= 1) { if (t < s) dred[t] += dred[t + s]; __syncthreads(); }
        double S_cs = dred[0];
        __syncthreads();
        double ss = 0.0;
        for (int k = 0; k < 32; ++k) ss += (double)sq[t + 256 * k];
        dred[t] = ss;
        __syncthreads();
        for (int s = 128; s > 0; s >>= 1) { if (t < s) dred[t] += dred[t + s]; __syncthreads(); }
        if (t == 0) {
            double nf = (double)N_TOTAL;
            double sum_l2 = 2.0 * nf * dred[0] - 2.0 * S_cs;
            if (sum_l2 < 0.0) sum_l2 = 0.0;
            double bw = sum_l2 / (nf * nf - nf) / 4.0;
            scal[0] = (float)(-1.0 / (16.0 * bw));
        }
    }
}

// ---------------------------------------------------------------------------
// 3) main: R4's proven BK=32 double-buffer, linear staging, compiler-scheduled
//    __syncthreads pipeline + fused last-block final reduction
// ---------------------------------------------------------------------------
__global__ __launch_bounds__(256, 4) void k_main(const unsigned short* __restrict__ X,
                                                 const unsigned short* __restrict__ XU,
                                                 const float* __restrict__ sq,
                                                 const float* __restrict__ scal,
                                                 double* __restrict__ partials,
                                                 unsigned* __restrict__ ctr,
                                                 float* __restrict__ out) {
    // XCD-contiguous bid swizzle (2080 = 8*260, bijective)
    int bid = (blockIdx.x & 7) * (NTRI / 8) + (blockIdx.x >> 3);
    int bi = 0, rem = bid;
    while (rem >= NB - bi) { rem -= NB - bi; ++bi; }
    int bj = bi + rem;

    int tid = threadIdx.x, lane = tid & 63, wid = tid >> 6;
    int wr = wid >> 1, wc = wid & 1;
    int lrow = lane & 15, kgrp = lane >> 4;

    __shared__ unsigned short Abuf[2 * 128 * 32];   // [buf][row][32 k-shorts]
    __shared__ unsigned short Bbuf[2 * 128 * 32];
    __shared__ double dred2[256];
    __shared__ float red[4];
    __shared__ unsigned lastflag;
    char* AB = (char*)Abuf;
    char* BB = (char*)Bbuf;

    f32x4 acc[4][4];
#pragma unroll
    for (int a = 0; a < 4; ++a)
#pragma unroll
        for (int b = 0; b < 4; ++b) acc[a][b] = (f32x4){0.f, 0.f, 0.f, 0.f};

    // staging: LINEAR source & dest (thread tid -> row tid>>2 (+64), chunk tid&3)
    const unsigned short* gA0 = X + ((size_t)bi * 128 + (tid >> 2)) * DDIM + (tid & 3) * 8;
    const unsigned short* gA1 = gA0 + (size_t)64 * DDIM;
    const unsigned short* gB0 = X + ((size_t)bj * 128 + (tid >> 2)) * DDIM + (tid & 3) * 8;
    const unsigned short* gB1 = gB0 + (size_t)64 * DDIM;
    int lds0 = tid * 16;
    int aoff = (wr * 64 + lrow) * 64 + kgrp * 16;
    int boff = (wc * 64 + lrow) * 64 + kgrp * 16;

#define STAGE(BS, KS) do { \
    gload_lds16(gA0 + (KS) * 32, AB + (BS) * 8192 + lds0); \
    gload_lds16(gA1 + (KS) * 32, AB + (BS) * 8192 + lds0 + 4096); \
    gload_lds16(gB0 + (KS) * 32, BB + (BS) * 8192 + lds0); \
    gload_lds16(gB1 + (KS) * 32, BB + (BS) * 8192 + lds0 + 4096); \
} while (0)

#define COMPUTE(BS) do { \
    bf16x8 af[4], bf_[4]; \
    _Pragma("unroll") \
    for (int f = 0; f < 4; ++f) { \
        af[f]  = *reinterpret_cast<const bf16x8*>(AB + (BS) * 8192 + aoff + f * 1024); \
        bf_[f] = *reinterpret_cast<const bf16x8*>(BB + (BS) * 8192 + boff + f * 1024); \
    } \
    _Pragma("unroll") \
    for (int a = 0; a < 4; ++a) \
        _Pragma("unroll") \
        for (int b = 0; b < 4; ++b) \
            acc[a][b] = __builtin_amdgcn_mfma_f32_16x16x32_bf16(af[a], bf_[b], acc[a][b], 0, 0, 0); \
} while (0)

    STAGE(0, 0);
    __syncthreads();
#pragma unroll
    for (int t = 0; t < K_STEPS - 1; ++t) {
        STAGE((t + 1) & 1, t + 1);     // issue next-slice loads first
        COMPUTE(t & 1);                // compute current slice
        __syncthreads();               // drain + protect
    }

    // light epilogue prefetch (small reg footprint) overlapping final MFMAs
    int i0 = bi * 128 + wr * 64;
    int j0 = bj * 128 + wc * 64;
    f32x4 sqin[4];
#pragma unroll
    for (int f = 0; f < 4; ++f)
        sqin[f] = *reinterpret_cast<const f32x4*>(sq + i0 + f * 16 + kgrp * 4);
    float sqjn[4];
#pragma unroll
    for (int g = 0; g < 4; ++g) sqjn[g] = sq[j0 + g * 16 + lrow];
    float nbv = scal[0];

    COMPUTE(1);                        // last K-slice (ks=7)

    const unsigned short* AU = XU + (size_t)(i0 + lrow) * 32 + kgrp * 8;
    const unsigned short* BU = XU + (size_t)(j0 + lrow) * 32 + kgrp * 8;
    bf16x8 au[4];
#pragma unroll
    for (int f = 0; f < 4; ++f)
        au[f] = *reinterpret_cast<const bf16x8*>(AU + (size_t)f * 16 * 32);

#pragma unroll
    for (int f = 0; f < 4; ++f) sqin[f] *= nbv;
#pragma unroll
    for (int g = 0; g < 4; ++g) sqjn[g] *= nbv;
    float m2nb = -2.f * nbv;

    f32x2 lp2 = (f32x2){0.f, 0.f};
#pragma unroll
    for (int g = 0; g < 4; ++g) {
        bf16x8 bu = *reinterpret_cast<const bf16x8*>(BU + (size_t)g * 16 * 32);
        f32x4 wf[4];
#pragma unroll
        for (int f = 0; f < 4; ++f)
            wf[f] = __builtin_amdgcn_mfma_f32_16x16x32_bf16(au[f], bu, (f32x4){0.f,0.f,0.f,0.f}, 0, 0, 0);
#pragma unroll
        for (int f = 0; f < 4; ++f) {
#pragma unroll
            for (int h = 0; h < 2; ++h) {
                f32x2 ssn = (f32x2){ sqin[f][2*h] + sqjn[g], sqin[f][2*h+1] + sqjn[g] };
                f32x2 tt  = (f32x2){ fmaf(acc[f][g][2*h],   m2nb, ssn.x),
                                     fmaf(acc[f][g][2*h+1], m2nb, ssn.y) };
                tt.x = fminf(tt.x, 0.f);
                tt.y = fminf(tt.y, 0.f);
                f32x2 e;
                e.x = __expf(tt.x);
                e.y = __expf(tt.y);
                f32x2 e2 = e * e, e4 = e2 * e2, e8 = e4 * e4, e16 = e8 * e8;
                f32x2 ks = ((e + e2) + (e4 + e8)) + e16;
                lp2.x = fmaf(wf[f][2*h],   ks.x, lp2.x);
                lp2.y = fmaf(wf[f][2*h+1], ks.y, lp2.y);
            }
        }
    }
    float lp = lp2.x + lp2.y;

#pragma unroll
    for (int off = 32; off > 0; off >>= 1) lp += __shfl_xor(lp, off);
    if (lane == 0) red[wid] = lp;
    __syncthreads();
    if (tid == 0) {
        partials[bid] = (double)((red[0] + red[1]) + (red[2] + red[3])) * ((bi == bj) ? 1.0 : 2.0);
        __threadfence();
        unsigned old = atomicAdd(ctr, 1u);
        lastflag = (old == NTRI - 1) ? 1u : 0u;
    }
    __syncthreads();

    if (lastflag) {                    // last block: fixed-order final reduction
        __threadfence();
        const volatile double* vp = partials;
        double s = 0.0;
        for (int k = 0; k < 9; ++k) {
            int idx = tid + 256 * k;
            if (idx < NTRI) s += vp[idx];
        }
        dred2[tid] = s;
        __syncthreads();
        for (int st = 128; st > 0; st >>= 1) {
            if (tid < st) dred2[tid] += dred2[tid + st];
            __syncthreads();
        }
        if (tid == 0) out[0] = (float)(dred2[0] / (double)scal[5]);
    }
#undef STAGE
#undef COMPUTE
}

extern "C" void kernel_launch(void* const* d_in, const int* in_sizes, int n_in,
                              void* d_out, int out_size, void* d_ws, size_t ws_size,
                              hipStream_t stream) {
    const float* src    = (const float*)d_in[0];
    const float* tgt    = (const float*)d_in[1];
    const float* label  = (const float*)d_in[2];
    const float* logits = (const float*)d_in[3];

    char* ws = (char*)d_ws;
    unsigned short* X   = (unsigned short*)(ws + OFF_X);
    float* sq           = (float*)(ws + OFF_SQ);
    unsigned short* XU  = (unsigned short*)(ws + OFF_XU);
    float* colpart      = (float*)(ws + OFF_CP);
    float* clspart      = (float*)(ws + OFF_CLS);
    unsigned* prespart  = (unsigned*)(ws + OFF_PRES);
    float* scal         = (float*)(ws + OFF_SC);
    unsigned* ctr       = (unsigned*)(ws + OFF_CTR);
    double* partials    = (double*)(ws + OFF_PART);

    k_pre    <<<2144, 256, 0, stream>>>(src, tgt, label, logits, X, sq, colpart, clspart, prespart, ctr);
    k_scales <<<33,   256, 0, stream>>>(clspart, prespart, colpart, sq, label, logits, scal, XU);
    k_main   <<<NTRI, 256, 0, stream>>>(X, XU, sq, scal, partials, ctr, (float*)d_out);
}

// Round 12
// 56.182 us; speedup vs baseline: 2.8842x; 1.7875x over previous
//
#include <hip/hip_runtime.h>
#include <hip/hip_bf16.h>

#define N_TOTAL 8192
#define BROWS   4096
#define DDIM    256
#define NCLS    10
#define NB      64              // 128-row tiles per side
#define NTRI    (NB*(NB+1)/2)   // 2080 upper-tri blocks (= 8*260)
#define K_STEPS 8               // BK=32

typedef __attribute__((ext_vector_type(8))) short bf16x8;
typedef __attribute__((ext_vector_type(4))) float f32x4;
typedef __attribute__((ext_vector_type(2))) float f32x2;

// ---- workspace layout (bytes) ----
static constexpr size_t OFF_X    = 0;              // 8192*256*2 = 4 MiB bf16 data
static constexpr size_t OFF_SQ   = 0x400000;       // 8192 f32 row sq-norms
static constexpr size_t OFF_XU   = 0x408000;       // 8192*32 bf16 padded weights
static constexpr size_t OFF_CP   = 0x488000;       // 64*256 f32 col partials
static constexpr size_t OFF_CLS  = 0x498000;       // 32*20 f32 class partials
static constexpr size_t OFF_PRES = 0x499000;       // 32 u32 presence partials
static constexpr size_t OFF_SC   = 0x49A000;       // 32 f32 scalars
static constexpr size_t OFF_PART = 0x49B000;       // 2080 f64 block partials

// scal: [0] = -1/(16*bw) (natural log), [5] = count_safe

__device__ __forceinline__ void gload_lds16(const void* g, void* l) {
    __builtin_amdgcn_global_load_lds((const __attribute__((address_space(1))) void*)g,
                                     (__attribute__((address_space(3))) void*)l, 16, 0, 0);
}
__device__ __forceinline__ float rne_bf16_val(float x) {
    unsigned b = __float_as_uint(x);
    unsigned r = (b + 0x7FFFu + ((b >> 16) & 1u)) >> 16;
    return __uint_as_float(r << 16);
}

// ---------------------------------------------------------------------------
// 1) fused pre-pass:
//    blocks 0..2047    : rows -> bf16 X + row sq-norms
//    blocks 2048..2111 : column sums (recomputed from f32 src with same RNE)
//    blocks 2112..2143 : class sums + argmax presence
// ---------------------------------------------------------------------------
__global__ void k_pre(const float* __restrict__ src, const float* __restrict__ tgt,
                      const float* __restrict__ label, const float* __restrict__ logits,
                      unsigned short* __restrict__ X, float* __restrict__ sq,
                      float* __restrict__ colpart, float* __restrict__ clspart,
                      unsigned* __restrict__ prespart) {
    __shared__ float shbuf[8][256];
    __shared__ float cbuf[256][NCLS];
    __shared__ unsigned pm[128];
    int t = threadIdx.x;
    int bid = blockIdx.x;

    if (bid < 2048) {                 // ---- prep path
        int wid  = t >> 6;
        int lane = t & 63;
        int row  = bid * 4 + wid;
        const float* p = (row < BROWS) ? (src + (size_t)row * DDIM)
                                       : (tgt + (size_t)(row - BROWS) * DDIM);
        f32x4 v = *reinterpret_cast<const f32x4*>(p + lane * 4);
        unsigned short h[4];
        float ssum = 0.f;
#pragma unroll
        for (int e = 0; e < 4; ++e) {
            unsigned bits = __float_as_uint(v[e]);
            unsigned r = (bits + 0x7FFFu + ((bits >> 16) & 1u)) >> 16;
            h[e] = (unsigned short)r;
            float f = __uint_as_float(r << 16);
            ssum += f * f;
        }
        ushort4 us; us.x = h[0]; us.y = h[1]; us.z = h[2]; us.w = h[3];
        *reinterpret_cast<ushort4*>(X + (size_t)row * DDIM + lane * 4) = us;
#pragma unroll
        for (int off = 32; off > 0; off >>= 1) ssum += __shfl_xor(ssum, off);
        if (lane == 0) sq[row] = ssum;
    } else if (bid < 2112) {          // ---- colsum path (from f32 source, RNE inline)
        int b  = bid - 2048;          // 0..63 -> rows b*128..+127
        int cg = t & 31;              // 8-dim column chunk
        int rs = t >> 5;              // row sub-stripe 0..7
        const float* base = (b < 32)
            ? (src + ((size_t)(b * 128 + rs)) * DDIM + cg * 8)
            : (tgt + ((size_t)((b - 32) * 128 + rs)) * DDIM + cg * 8);
        float a[8];
#pragma unroll
        for (int e = 0; e < 8; ++e) a[e] = 0.f;
        for (int i = 0; i < 16; ++i) {
            const float* rp = base + (size_t)i * 8 * DDIM;
            f32x4 v0 = *reinterpret_cast<const f32x4*>(rp);
            f32x4 v1 = *reinterpret_cast<const f32x4*>(rp + 4);
#pragma unroll
            for (int e = 0; e < 4; ++e) a[e]     += rne_bf16_val(v0[e]);
#pragma unroll
            for (int e = 0; e < 4; ++e) a[4 + e] += rne_bf16_val(v1[e]);
        }
#pragma unroll
        for (int e = 0; e < 8; ++e) shbuf[rs][cg * 8 + e] = a[e];
        __syncthreads();
        float s = 0.f;
#pragma unroll
        for (int k = 0; k < 8; ++k) s += shbuf[k][t];
        colpart[b * DDIM + t] = s;
    } else {                          // ---- class-sum path
        int b = bid - 2112;           // 0..31
        int r = b * 128 + (t & 127);
        if (t < 128) {
            const float* lr = label + (size_t)r * NCLS;
#pragma unroll
            for (int c = 0; c < NCLS; ++c) cbuf[t][c] = lr[c];
        } else {
            const float* gr = logits + (size_t)r * NCLS;
            float bv = -1e30f; int bc = 0;
#pragma unroll
            for (int c = 0; c < NCLS; ++c) {
                float v = gr[c];
                cbuf[t][c] = v;
                if (v > bv) { bv = v; bc = c; }
            }
            pm[t - 128] = 1u << bc;
        }
        __syncthreads();
        if (t < NCLS) {
            float a = 0.f;
            for (int i = 0; i < 128; ++i) a += cbuf[i][t];
            clspart[b * 20 + t] = a;
        } else if (t < 2 * NCLS) {
            float a = 0.f;
            for (int i = 128; i < 256; ++i) a += cbuf[i][t - NCLS];
            clspart[b * 20 + t] = a;
        }
        if (t == 0) {
            unsigned p = 0;
            for (int i = 0; i < 128; ++i) p |= pm[i];
            prespart[b] = p;
        }
    }
}

// ---------------------------------------------------------------------------
// 2) scales + XU build fused (33 blocks): every block redundantly derives the
//    class scales; blocks 0..31 write XU rows; block 32 computes bandwidth.
// ---------------------------------------------------------------------------
__global__ void k_scales(const float* __restrict__ clspart, const unsigned* __restrict__ prespart,
                         const float* __restrict__ colpart, const float* __restrict__ sq,
                         const float* __restrict__ label, const float* __restrict__ logits,
                         float* __restrict__ scal, unsigned short* __restrict__ XU) {
    __shared__ float  cfin[2 * NCLS];
    __shared__ float  ascale[NCLS], bscale[NCLS];
    __shared__ unsigned presAll;
    __shared__ double dred[256];
    int t = threadIdx.x, b = blockIdx.x;

    if (t < 2 * NCLS) {
        float a = 0.f;
        for (int k = 0; k < 32; ++k) a += clspart[k * 20 + t];
        cfin[t] = a;
    }
    if (t == 0) {
        unsigned p = 0;
        for (int k = 0; k < 32; ++k) p |= prespart[k];
        presAll = p;
    }
    __syncthreads();
    if (t == 0) {
        int count = 0;
        for (int c = 0; c < NCLS; ++c) {
            float sv = cfin[c], tv = cfin[NCLS + c];
            bool m = (sv > 0.f) && ((presAll >> c) & 1u);
            count += m ? 1 : 0;
            float sdiv = (sv == 0.f) ? 100.f : sv;
            float tdiv = (tv == 0.f) ? 100.f : tv;
            ascale[c] = m ? (1.f / sdiv) : 0.f;
            bscale[c] = m ? (1.f / tdiv) : 0.f;
        }
        if (b == 32) scal[5] = (float)(count > 0 ? count : 1);
    }
    __syncthreads();

    if (b < 32) {                     // ---- XU rows
        int r = b * 256 + t;
        float v[NCLS];
        if (r < BROWS) {
            const float* lr = label + (size_t)r * NCLS;
#pragma unroll
            for (int c = 0; c < NCLS; ++c) v[c] = lr[c] * ascale[c];
        } else {
            const float* gr = logits + (size_t)(r - BROWS) * NCLS;
#pragma unroll
            for (int c = 0; c < NCLS; ++c) v[c] = -gr[c] * bscale[c];
        }
        unsigned packed[16];
#pragma unroll
        for (int w = 0; w < 16; ++w) {
            unsigned lo = 0, hi = 0;
            if (2 * w < NCLS) {
                unsigned bits = __float_as_uint(v[2 * w]);
                lo = (bits + 0x7FFFu + ((bits >> 16) & 1u)) >> 16;
            }
            if (2 * w + 1 < NCLS) {
                unsigned bits = __float_as_uint(v[2 * w + 1]);
                hi = (bits + 0x7FFFu + ((bits >> 16) & 1u)) >> 16;
            }
            packed[w] = lo | (hi << 16);
        }
        uint4* out = reinterpret_cast<uint4*>(XU + (size_t)r * 32);
#pragma unroll
        for (int q = 0; q < 4; ++q)
            out[q] = make_uint4(packed[4*q], packed[4*q+1], packed[4*q+2], packed[4*q+3]);
    } else {                          // ---- bandwidth (block 32)
        double cd = 0.0;
        for (int k = 0; k < 64; ++k) cd += (double)colpart[k * DDIM + t];
        dred[t] = cd * cd;
        __syncthreads();
        for (int s = 128; s > 0; s >>= 1) { if (t < s) dred[t] += dred[t + s]; __syncthreads(); }
        double S_cs = dred[0];
        __syncthreads();
        double ss = 0.0;
        for (int k = 0; k < 32; ++k) ss += (double)sq[t + 256 * k];
        dred[t] = ss;
        __syncthreads();
        for (int s = 128; s > 0; s >>= 1) { if (t < s) dred[t] += dred[t + s]; __syncthreads(); }
        if (t == 0) {
            double nf = (double)N_TOTAL;
            double sum_l2 = 2.0 * nf * dred[0] - 2.0 * S_cs;
            if (sum_l2 < 0.0) sum_l2 = 0.0;
            double bw = sum_l2 / (nf * nf - nf) / 4.0;
            scal[0] = (float)(-1.0 / (16.0 * bw));
        }
    }
}

// ---------------------------------------------------------------------------
// 3) main: BK=32 double-buffered 2-phase pipeline, bank-balanced linear LDS,
//    MFMA Gram + MFMA weights + packed 1-exp kernel chain.
//    NO device-scope fences/atomics here (threadfence -> L2 writeback was the
//    R5-R11 regression); final reduction is a separate dispatch.
// ---------------------------------------------------------------------------
__global__ __launch_bounds__(256, 3) void k_main(const unsigned short* __restrict__ X,
                                                 const unsigned short* __restrict__ XU,
                                                 const float* __restrict__ sq,
                                                 const float* __restrict__ scal,
                                                 double* __restrict__ partials) {
    // XCD-contiguous bid swizzle (2080 = 8*260, bijective)
    int bid = (blockIdx.x & 7) * (NTRI / 8) + (blockIdx.x >> 3);
    int bi = 0, rem = bid;
    while (rem >= NB - bi) { rem -= NB - bi; ++bi; }
    int bj = bi + rem;

    int tid = threadIdx.x, lane = tid & 63, wid = tid >> 6;
    int wr = wid >> 1, wc = wid & 1;
    int lrow = lane & 15, kgrp = lane >> 4;

    __shared__ unsigned short Abuf[2 * 128 * 32];   // [buf][row][32 k-shorts]
    __shared__ unsigned short Bbuf[2 * 128 * 32];
    __shared__ float red[4];
    char* AB = (char*)Abuf;
    char* BB = (char*)Bbuf;

    float nb = scal[0];

    f32x4 acc[4][4];
#pragma unroll
    for (int a = 0; a < 4; ++a)
#pragma unroll
        for (int b = 0; b < 4; ++b) acc[a][b] = (f32x4){0.f, 0.f, 0.f, 0.f};

    // staging pointers: thread = chunk tid (row tid>>2, col-chunk tid&3), +64 rows
    const unsigned short* gA0 = X + ((size_t)bi * 128 + (tid >> 2)) * DDIM + (tid & 3) * 8;
    const unsigned short* gA1 = gA0 + (size_t)64 * DDIM;
    const unsigned short* gB0 = X + ((size_t)bj * 128 + (tid >> 2)) * DDIM + (tid & 3) * 8;
    const unsigned short* gB1 = gB0 + (size_t)64 * DDIM;
    int lds0 = tid * 16;                                  // linear LDS chunk
    int aoff = (wr * 64 + lrow) * 64 + kgrp * 16;         // ds_read base (bytes)
    int boff = (wc * 64 + lrow) * 64 + kgrp * 16;

#define STAGE(BS, KS) do { \
    gload_lds16(gA0 + (KS) * 32, AB + (BS) * 8192 + lds0); \
    gload_lds16(gA1 + (KS) * 32, AB + (BS) * 8192 + lds0 + 4096); \
    gload_lds16(gB0 + (KS) * 32, BB + (BS) * 8192 + lds0); \
    gload_lds16(gB1 + (KS) * 32, BB + (BS) * 8192 + lds0 + 4096); \
} while (0)

#define COMPUTE(BS) do { \
    bf16x8 af[4], bf[4]; \
    _Pragma("unroll") \
    for (int f = 0; f < 4; ++f) { \
        af[f] = *reinterpret_cast<const bf16x8*>(AB + (BS) * 8192 + aoff + f * 1024); \
        bf[f] = *reinterpret_cast<const bf16x8*>(BB + (BS) * 8192 + boff + f * 1024); \
    } \
    _Pragma("unroll") \
    for (int a = 0; a < 4; ++a) \
        _Pragma("unroll") \
        for (int b = 0; b < 4; ++b) \
            acc[a][b] = __builtin_amdgcn_mfma_f32_16x16x32_bf16(af[a], bf[b], acc[a][b], 0, 0, 0); \
} while (0)

    STAGE(0, 0);
    __syncthreads();
#pragma unroll
    for (int t = 0; t < K_STEPS - 1; ++t) {
        STAGE((t + 1) & 1, t + 1);     // issue next-slice loads first
        COMPUTE(t & 1);                // compute current slice
        __syncthreads();               // drain + protect
    }

    // ---- epilogue operand prefetch (overlaps with final compute)
    int i0 = bi * 128 + wr * 64;
    int j0 = bj * 128 + wc * 64;
    const unsigned short* AU = XU + (size_t)(i0 + lrow) * 32 + kgrp * 8;
    const unsigned short* BU = XU + (size_t)(j0 + lrow) * 32 + kgrp * 8;
    bf16x8 au[4], bu[4];
#pragma unroll
    for (int f = 0; f < 4; ++f) {
        au[f] = *reinterpret_cast<const bf16x8*>(AU + (size_t)f * 16 * 32);
        bu[f] = *reinterpret_cast<const bf16x8*>(BU + (size_t)f * 16 * 32);
    }
    f32x4 sqin[4];
#pragma unroll
    for (int f = 0; f < 4; ++f)
        sqin[f] = *reinterpret_cast<const f32x4*>(sq + i0 + f * 16 + kgrp * 4);
    float sqjn[4];
#pragma unroll
    for (int g = 0; g < 4; ++g) sqjn[g] = sq[j0 + g * 16 + lrow];

    COMPUTE((K_STEPS - 1) & 1);        // last K-slice

    // pre-scale by nb (natural-log exponent scale); clamp moves to fmin after scale
#pragma unroll
    for (int f = 0; f < 4; ++f) sqin[f] *= nb;
#pragma unroll
    for (int g = 0; g < 4; ++g) sqjn[g] *= nb;
    float m2nb = -2.f * nb;

    f32x2 lp2 = (f32x2){0.f, 0.f};
#pragma unroll
    for (int g = 0; g < 4; ++g) {
        f32x4 wf[4];
#pragma unroll
        for (int f = 0; f < 4; ++f)
            wf[f] = __builtin_amdgcn_mfma_f32_16x16x32_bf16(au[f], bu[g], (f32x4){0.f,0.f,0.f,0.f}, 0, 0, 0);
#pragma unroll
        for (int f = 0; f < 4; ++f) {
#pragma unroll
            for (int h = 0; h < 2; ++h) {
                f32x2 ssn = (f32x2){ sqin[f][2*h] + sqjn[g], sqin[f][2*h+1] + sqjn[g] };
                f32x2 tt  = (f32x2){ fmaf(acc[f][g][2*h],   m2nb, ssn.x),
                                     fmaf(acc[f][g][2*h+1], m2nb, ssn.y) };
                tt.x = fminf(tt.x, 0.f);
                tt.y = fminf(tt.y, 0.f);
                f32x2 e;
                e.x = __expf(tt.x);
                e.y = __expf(tt.y);
                f32x2 e2 = e * e, e4 = e2 * e2, e8 = e4 * e4, e16 = e8 * e8;
                f32x2 ks = ((e + e2) + (e4 + e8)) + e16;
                lp2.x = fmaf(wf[f][2*h],   ks.x, lp2.x);
                lp2.y = fmaf(wf[f][2*h+1], ks.y, lp2.y);
            }
        }
    }
    float lp = lp2.x + lp2.y;

#pragma unroll
    for (int off = 32; off > 0; off >>= 1) lp += __shfl_xor(lp, off);
    if (lane == 0) red[wid] = lp;
    __syncthreads();
    if (tid == 0)
        partials[bid] = (double)((red[0] + red[1]) + (red[2] + red[3])) * ((bi == bj) ? 1.0 : 2.0);
#undef STAGE
#undef COMPUTE
}

// ---------------------------------------------------------------------------
// 4) final fixed-order reduction, divide by count (separate dispatch: the
//    kernel boundary provides cross-XCD visibility without L2-writeback fences)
// ---------------------------------------------------------------------------
__global__ void k_final(const double* __restrict__ partials, const float* __restrict__ scal,
                        float* __restrict__ out) {
    __shared__ double dred[256];
    int t = threadIdx.x;
    double s = 0.0;
    for (int k = 0; k < 9; ++k) {
        int idx = t + 256 * k;
        if (idx < NTRI) s += partials[idx];
    }
    dred[t] = s;
    __syncthreads();
    for (int st = 128; st > 0; st >>= 1) { if (t < st) dred[t] += dred[t + st]; __syncthreads(); }
    if (t == 0) out[0] = (float)(dred[0] / (double)scal[5]);
}

extern "C" void kernel_launch(void* const* d_in, const int* in_sizes, int n_in,
                              void* d_out, int out_size, void* d_ws, size_t ws_size,
                              hipStream_t stream) {
    const float* src    = (const float*)d_in[0];
    const float* tgt    = (const float*)d_in[1];
    const float* label  = (const float*)d_in[2];
    const float* logits = (const float*)d_in[3];

    char* ws = (char*)d_ws;
    unsigned short* X   = (unsigned short*)(ws + OFF_X);
    float* sq           = (float*)(ws + OFF_SQ);
    unsigned short* XU  = (unsigned short*)(ws + OFF_XU);
    float* colpart      = (float*)(ws + OFF_CP);
    float* clspart      = (float*)(ws + OFF_CLS);
    unsigned* prespart  = (unsigned*)(ws + OFF_PRES);
    float* scal         = (float*)(ws + OFF_SC);
    double* partials    = (double*)(ws + OFF_PART);

    k_pre    <<<2144, 256, 0, stream>>>(src, tgt, label, logits, X, sq, colpart, clspart, prespart);
    k_scales <<<33,   256, 0, stream>>>(clspart, prespart, colpart, sq, label, logits, scal, XU);
    k_main   <<<NTRI, 256, 0, stream>>>(X, XU, sq, scal, partials);
    k_final  <<<1,    256, 0, stream>>>(partials, scal, (float*)d_out);
}